// Round 6
// baseline (407.115 us; speedup 1.0000x reference)
//
#include <hip/hip_runtime.h>
#include <hip/hip_bf16.h>
#include <stdint.h>
#include <stddef.h>

// out[M,N] = X[M,K] @ sign(W[N,K])^T + bias[N];  M=N=K=4096, fp32 in/out.
// R6 (= R5 resubmit after infra failure): SINGLE FUSED KERNEL. fp32->bf16 (x)
// and fp32->sign->bf16 (w) conversions done in-flight during staging
// (reg-staged, T14 issue-early/write-late). No prep kernel; d_ws unused.
// GEMM core = R1's verified best (4-phase 16x16x32, 132us GEMM dispatch):
// same fragment reads, same MFMA order, same granule-XOR LDS layout ->
// identical accumulation numerics (absmax 2.0 lineage).
#define M_DIM 4096
#define N_DIM 4096
#define K_DIM 4096
#define BM 256
#define BN 256
#define BK 64
#define NKT (K_DIM / BK)          // 64 K-tiles

static_assert(M_DIM % BM == 0 && N_DIM % BN == 0 && K_DIM % BK == 0, "tiling");

typedef __bf16 bf16;
typedef __attribute__((ext_vector_type(8))) __bf16 bf16x8;
typedef __attribute__((ext_vector_type(4))) float f32x4;

__global__ __launch_bounds__(512, 2) void gemm_bin_fused(const float* __restrict__ A,
                                                         const float* __restrict__ W,
                                                         const float* __restrict__ bias,
                                                         float* __restrict__ C) {
    // LDS layout (verified): row = 64 bf16 = 128 B = 8 granules of 16 B;
    // granule g of row r lives at slot s = g ^ (r&7) (conflict-free).
    __shared__ __align__(16) bf16 As[2][BM * BK];   // 2 x 32 KB
    __shared__ __align__(16) bf16 Bs[2][BM * BK];   // 2 x 32 KB

    const int tid  = threadIdx.x;
    const int lane = tid & 63;
    const int wave = tid >> 6;        // 0..7
    const int wm   = wave >> 2;       // 0..1 (M half)
    const int wn   = wave & 3;        // 0..3 (N quarter)

    const int tileM = blockIdx.y * BM;
    const int tileN = blockIdx.x * BN;

    // ---- reg-staging geometry -------------------------------------------
    // Round r (0..3) covers rows r*64..r*64+63. Thread: row r*64 + (tid>>3),
    // granule tid&7 (8 fp32 = 2 dwordx4). ds_write_b128 to swizzled slot
    // sG ^ (sRow&7): per 8-lane group slots are a permutation -> conflict-free
    // (same algebra as the verified gload_lds placement).
    const int sRow  = tid >> 3;            // 0..63
    const int sG    = tid & 7;             // granule
    const int sSlot = sG ^ (sRow & 7);
    const float* aBase = A + (size_t)(tileM + sRow) * K_DIM + sG * 8;
    const float* wBase = W + (size_t)(tileN + sRow) * K_DIM + sG * 8;
    const int ldsOff = sRow * BK + sSlot * 8;   // bf16 elems; + r*64*BK per round

#define ISSUE(DST_, BASE_, KB_) \
    _Pragma("unroll") \
    for (int r = 0; r < 4; ++r) { \
        DST_[2 * r]     = *(const f32x4*)(BASE_ + (size_t)r * 64 * K_DIM + (KB_)); \
        DST_[2 * r + 1] = *(const f32x4*)(BASE_ + (size_t)r * 64 * K_DIM + (KB_) + 4); \
    }

// x: plain RNE cast (same numerics as the old prep kernel).
#define CVTWR_A(BUF_, SRC_) \
    _Pragma("unroll") \
    for (int r = 0; r < 4; ++r) { \
        bf16x8 v; \
        _Pragma("unroll") \
        for (int e = 0; e < 4; ++e) { \
            v[e]     = (bf16)SRC_[2 * r][e]; \
            v[4 + e] = (bf16)SRC_[2 * r + 1][e]; \
        } \
        *(bf16x8*)&As[BUF_][r * 64 * BK + ldsOff] = v; \
    }

// w: sign() then bf16 (identical expression to the old prep kernel).
#define SGN(F_) ((bf16)(((F_) > 0.f) ? 1.f : (((F_) < 0.f) ? -1.f : 0.f)))
#define CVTWR_B(BUF_, SRC_) \
    _Pragma("unroll") \
    for (int r = 0; r < 4; ++r) { \
        bf16x8 v; \
        _Pragma("unroll") \
        for (int e = 0; e < 4; ++e) { \
            v[e]     = SGN(SRC_[2 * r][e]); \
            v[4 + e] = SGN(SRC_[2 * r + 1][e]); \
        } \
        *(bf16x8*)&Bs[BUF_][r * 64 * BK + ldsOff] = v; \
    }

    f32x4 acc[8][4];
#pragma unroll
    for (int i = 0; i < 8; ++i)
#pragma unroll
        for (int j = 0; j < 4; ++j)
            acc[i][j] = (f32x4){0.f, 0.f, 0.f, 0.f};

    bf16x8 bfr[4][2];   // B-frags, read once per tile at ph0 top (R1-verified)

    // Fragment reads (R1-verified): lane = qf*16 + l15; granule g = kk*4+qf at
    // row base+l15; slot s = g ^ (l15&7).
    const int l15 = lane & 15;
    const int qf  = lane >> 4;
    const int fragRowA = wm * 128 + l15;
    const int fragRowB = wn * 64 + l15;
    const int s0 = (0 + qf) ^ (l15 & 7);   // kk=0
    const int s1 = (4 + qf) ^ (l15 & 7);   // kk=1

#define READ_A(B_, P_) \
    _Pragma("unroll") \
    for (int ii = 0; ii < 2; ++ii) { \
        af[ii][0] = *(const bf16x8*)&As[B_][(fragRowA + (2 * (P_) + ii) * 16) * BK + s0 * 8]; \
        af[ii][1] = *(const bf16x8*)&As[B_][(fragRowA + (2 * (P_) + ii) * 16) * BK + s1 * 8]; \
    }

#define READ_B(B_) \
    _Pragma("unroll") \
    for (int j = 0; j < 4; ++j) { \
        bfr[j][0] = *(const bf16x8*)&Bs[B_][(fragRowB + j * 16) * BK + s0 * 8]; \
        bfr[j][1] = *(const bf16x8*)&Bs[B_][(fragRowB + j * 16) * BK + s1 * 8]; \
    }

#define MFMA16(P_) \
    _Pragma("unroll") \
    for (int ii = 0; ii < 2; ++ii) \
        _Pragma("unroll") \
        for (int j = 0; j < 4; ++j) { \
            acc[2 * (P_) + ii][j] = __builtin_amdgcn_mfma_f32_16x16x32_bf16(af[ii][0], bfr[j][0], acc[2 * (P_) + ii][j], 0, 0, 0); \
            acc[2 * (P_) + ii][j] = __builtin_amdgcn_mfma_f32_16x16x32_bf16(af[ii][1], bfr[j][1], acc[2 * (P_) + ii][j], 0, 0, 0); \
        }

#define VMCNT0 asm volatile("s_waitcnt vmcnt(0)" ::: "memory")
#define LGKM0  asm volatile("s_waitcnt lgkmcnt(0)" ::: "memory")
#define BAR    __builtin_amdgcn_s_barrier()
#define SCHED0 __builtin_amdgcn_sched_barrier(0)
#define PRIO1  __builtin_amdgcn_s_setprio(1)
#define PRIO0  __builtin_amdgcn_s_setprio(0)

    // Hazard ledger (tile t computes buf B_, stages tile t+1 into B_^1):
    //  - A-loads issued ph1, drained ph2 (vmcnt0; ~1 phase of latency cover).
    //  - B-loads issued ph2 (after the A drain), drained ph3.
    //  - A ds_writes (ph2) + B ds_writes (ph3) published by ph3's LGKM0 +
    //    closing barrier, strictly before t+1.ph0 reads of buf^1.
    //  - Writes into buf^1: last reads of buf^1 (t-1.ph3-top A / t-1.ph0-top B)
    //    retired >=2 barriers earlier. No gload_lds -> vmcnt counts only ours.
    //  - All barriers on uniform control flow (no divergence-deadlock path).
#define KTILE(B_, KN_) do { \
        { bf16x8 af[2][2]; \
          READ_B(B_); READ_A(B_, 0); \
          BAR; PRIO1; MFMA16(0); PRIO0; BAR; SCHED0; } \
        { bf16x8 af[2][2]; \
          READ_A(B_, 1); \
          ISSUE(aLd, aBase, KN_); \
          BAR; PRIO1; MFMA16(1); PRIO0; BAR; SCHED0; } \
        { bf16x8 af[2][2]; \
          READ_A(B_, 2); \
          VMCNT0; CVTWR_A((B_) ^ 1, aLd); SCHED0; \
          ISSUE(bLd, wBase, KN_); \
          BAR; PRIO1; MFMA16(2); PRIO0; BAR; SCHED0; } \
        { bf16x8 af[2][2]; \
          READ_A(B_, 3); \
          VMCNT0; CVTWR_B((B_) ^ 1, bLd); LGKM0; \
          BAR; PRIO1; MFMA16(3); PRIO0; BAR; SCHED0; } \
    } while (0)

    f32x4 aLd[8];   // staged A fp32 (live ph1->ph2 only)
    f32x4 bLd[8];   // staged B fp32 (live ph2->ph3 only)

    // ---- prologue: stage tile 0 into buf0 --------------------------------
    ISSUE(aLd, aBase, 0);
    ISSUE(bLd, wBase, 0);
    VMCNT0;
    CVTWR_A(0, aLd);
    CVTWR_B(0, bLd);
    LGKM0;
    BAR;
    SCHED0;

    // ---- main loop: 2 K-tiles per iteration (static buffer parity) --------
    // Tail stages k-offset 0 again (valid memory; target buffer never read
    // after that point) -> branch-free.
    for (int kt = 0; kt < NKT; kt += 2) {
        const int kn1 = (kt + 1 < NKT) ? (kt + 1) * BK : 0;   // stage tile kt+1
        KTILE(0, kn1);
        const int kn2 = (kt + 2 < NKT) ? (kt + 2) * BK : 0;   // stage tile kt+2
        KTILE(1, kn2);
    }

    // ---- epilogue: C/D layout col = lane&15, row = (lane>>4)*4 + reg ------
#pragma unroll
    for (int j = 0; j < 4; ++j) {
        const int col = tileN + wn * 64 + j * 16 + l15;
        const float bv = bias[col];
#pragma unroll
        for (int i = 0; i < 8; ++i) {
            const int row0 = tileM + wm * 128 + i * 16 + (qf << 2);
#pragma unroll
            for (int rr = 0; rr < 4; ++rr) {
                C[(size_t)(row0 + rr) * N_DIM + col] = acc[i][j][rr] + bv;
            }
        }
    }

#undef ISSUE
#undef CVTWR_A
#undef CVTWR_B
#undef SGN
#undef READ_A
#undef READ_B
#undef MFMA16
#undef VMCNT0
#undef LGKM0
#undef BAR
#undef SCHED0
#undef PRIO1
#undef PRIO0
#undef KTILE
}

// ---------------------------------------------------------------------------
extern "C" void kernel_launch(void* const* d_in, const int* in_sizes, int n_in,
                              void* d_out, int out_size, void* d_ws, size_t ws_size,
                              hipStream_t stream) {
    const float* x    = (const float*)d_in[0];  // [M,K]
    const float* w    = (const float*)d_in[1];  // [N,K]
    const float* bias = (const float*)d_in[2];  // [N]
    float* out        = (float*)d_out;          // [M,N]

    dim3 grid(N_DIM / BN, M_DIM / BM);          // 16 x 16 = 256 blocks = 1/CU
    gemm_bin_fused<<<grid, 512, 0, stream>>>(x, w, bias, out);
}